// Round 6
// baseline (196.805 us; speedup 1.0000x reference)
//
#include <hip/hip_runtime.h>

#define N_ROWS 4096
#define TN 8192      // 2N
#define DIM 128
// z is pre-scaled by sqrt(10*log2(e)) so MFMA yields 10*log2e*sim directly:
// exp(10*s) = exp2( (sqrt(c)*zi) . (sqrt(c)*zj) ),  c = 10*log2(e)
#define SQRT_C 3.79828266f

// ws layout: [0,8192) f32 denom | [8192,9216) f32 pos_part | [9216] u32 ticket
//            | z bf16 at byte 40960
// R5 BUG: z was at byte 36864 == float index 9216 == &ticket -> prep's z-row-0
// store clobbered the ticket, finalize never fired, out stayed 0. z moved up.
#define Z_BYTE_OFF 40960
#define NBLOCKS_GEMM 1024   // grid (128, 8)

typedef __attribute__((ext_vector_type(8))) short short8;
typedef __attribute__((ext_vector_type(4))) float f32x4;

static __device__ __forceinline__ ushort f2bf(float f) {
    union { float f; unsigned u; } a; a.f = f;
    unsigned r = a.u + 0x7FFF + ((a.u >> 16) & 1);  // round-to-nearest-even
    return (ushort)(r >> 16);
}

// --- Kernel A: normalize -> scaled bf16 z; positives partial; zero denom/ticket ---
__global__ __launch_bounds__(256) void prep_kernel(
    const float* __restrict__ anchor, const float* __restrict__ target,
    ushort* __restrict__ z, float* __restrict__ pos_part,
    float* __restrict__ denom, unsigned* __restrict__ ticket)
{
    // zero denom (8 entries per block) and the ticket counter
    if (threadIdx.x < 8) denom[blockIdx.x * 8 + threadIdx.x] = 0.0f;
    if (blockIdx.x == 0 && threadIdx.x == 8) *ticket = 0u;

    int wave = threadIdx.x >> 6;
    int lane = threadIdx.x & 63;
    int i    = blockIdx.x * 4 + wave;
    float2 a = ((const float2*)(anchor + (size_t)i * DIM))[lane];
    float2 t = ((const float2*)(target + (size_t)i * DIM))[lane];
    float sa = a.x * a.x + a.y * a.y;
    float st = t.x * t.x + t.y * t.y;
    float dt = a.x * t.x + a.y * t.y;
    #pragma unroll
    for (int m = 1; m < 64; m <<= 1) {
        sa += __shfl_xor(sa, m, 64);
        st += __shfl_xor(st, m, 64);
        dt += __shfl_xor(dt, m, 64);
    }
    float rsa = rsqrtf(fmaxf(sa, 1e-12f));
    float rst = rsqrtf(fmaxf(st, 1e-12f));
    float ka = rsa * SQRT_C, kt = rst * SQRT_C;
    ushort2 za, zt;
    za.x = f2bf(a.x * ka); za.y = f2bf(a.y * ka);
    zt.x = f2bf(t.x * kt); zt.y = f2bf(t.y * kt);
    ((ushort2*)(z + (size_t)i * DIM))[lane] = za;
    ((ushort2*)(z + (size_t)(i + N_ROWS) * DIM))[lane] = zt;
    __shared__ float red[4];
    if (lane == 0) red[wave] = dt * rsa * rst;
    __syncthreads();
    if (threadIdx.x == 0)
        pos_part[blockIdx.x] = red[0] + red[1] + red[2] + red[3];
}

// --- Kernel B: denom_i += sum_j!=i exp2(z_i.z_j); last block computes the loss ---
// Block: 64 rows x 1024 cols, 4 waves as 2x2 -> wave owns 32 rows x 512 cols.
// A (32x128) PINNED in VGPRs (asm keep-alive defeats rematerialization — R4's
// VGPR=84 showed the compiler was re-loading A every tile). B streamed from L2
// with a 4-deep statically-named register rotation (loads issued 3 tiles early).
__global__ __launch_bounds__(256, 2) void simgemm_kernel(
    const ushort* __restrict__ z, float* __restrict__ denom,
    const float* __restrict__ pos_part, unsigned* __restrict__ ticket,
    float* __restrict__ out)
{
    int wave = threadIdx.x >> 6;
    int lane = threadIdx.x & 63;
    int r = lane & 15;       // A/B row-within-tile; C col
    int g = lane >> 4;       // k-group; C row group
    int wr = wave >> 1, wc = wave & 1;
    int rowbase = blockIdx.x * 64 + wr * 32;
    int wcol    = blockIdx.y * 1024 + wc * 512;

    // A fragments: 32 rows x 128 k resident (32 VGPR), pinned
    short8 a[2][4];
    #pragma unroll
    for (int rt = 0; rt < 2; ++rt)
        #pragma unroll
        for (int kt = 0; kt < 4; ++kt) {
            a[rt][kt] = *(const short8*)(z + (size_t)(rowbase + rt * 16 + r) * DIM
                                           + kt * 32 + g * 8);
            asm volatile("" : "+v"(*(f32x4*)&a[rt][kt]));  // forbid remat
        }

    float ps[2][4];
    #pragma unroll
    for (int rt = 0; rt < 2; ++rt)
        #pragma unroll
        for (int q = 0; q < 4; ++q) ps[rt][q] = 0.0f;

    bool wavediag = ((unsigned)(rowbase - wcol) < 512u);
    const ushort* pb = z + (size_t)(wcol + r) * DIM + g * 8;

#define LOADB(buf, t)                                                  \
    {   const ushort* p_ = pb + (size_t)(t) * (16 * DIM);              \
        buf[0] = *(const short8*)(p_);                                 \
        buf[1] = *(const short8*)(p_ + 32);                            \
        buf[2] = *(const short8*)(p_ + 64);                            \
        buf[3] = *(const short8*)(p_ + 96); }

#define COMPUTE(t, b)                                                         \
    {   int c0 = wcol + (t) * 16;                                             \
        bool dtile = wavediag && ((unsigned)(c0 - rowbase) < 32u);            \
        if (!dtile) {                                                         \
            _Pragma("unroll")                                                 \
            for (int rt = 0; rt < 2; ++rt) {                                  \
                f32x4 acc = {0.f, 0.f, 0.f, 0.f};                             \
                _Pragma("unroll")                                             \
                for (int kt = 0; kt < 4; ++kt)                                \
                    acc = __builtin_amdgcn_mfma_f32_16x16x32_bf16(            \
                        a[rt][kt], b[kt], acc, 0, 0, 0);                      \
                _Pragma("unroll")                                             \
                for (int q = 0; q < 4; ++q)                                   \
                    ps[rt][q] += __builtin_amdgcn_exp2f(acc[q]);              \
            }                                                                 \
        } else {                                                              \
            int gcol = c0 + r;                                                \
            _Pragma("unroll")                                                 \
            for (int rt = 0; rt < 2; ++rt) {                                  \
                f32x4 acc = {0.f, 0.f, 0.f, 0.f};                             \
                _Pragma("unroll")                                             \
                for (int kt = 0; kt < 4; ++kt)                                \
                    acc = __builtin_amdgcn_mfma_f32_16x16x32_bf16(            \
                        a[rt][kt], b[kt], acc, 0, 0, 0);                      \
                _Pragma("unroll")                                             \
                for (int q = 0; q < 4; ++q) {                                 \
                    float e = __builtin_amdgcn_exp2f(acc[q]);                 \
                    int grow = rowbase + rt * 16 + g * 4 + q;                 \
                    ps[rt][q] += (grow == gcol) ? 0.0f : e;                   \
                }                                                             \
            }                                                                 \
        } }

    // 32 tiles per wave; 4-deep rotation, loads lead their use by 3 tiles
    short8 b0[4], b1[4], b2[4], b3[4];
    LOADB(b0, 0); LOADB(b1, 1); LOADB(b2, 2);
    #pragma unroll
    for (int t = 0; t < 32; t += 4) {
        LOADB(b3, t + 3);
        COMPUTE(t, b0);
        LOADB(b0, (t + 4 <= 31 ? t + 4 : 31));
        COMPUTE(t + 1, b1);
        LOADB(b1, (t + 5 <= 31 ? t + 5 : 31));
        COMPUTE(t + 2, b2);
        LOADB(b2, (t + 6 <= 31 ? t + 6 : 31));
        COMPUTE(t + 3, b3);
    }
#undef LOADB
#undef COMPUTE

    // reduce across the 16 lanes sharing g, then one atomic per row
    #pragma unroll
    for (int rt = 0; rt < 2; ++rt)
        #pragma unroll
        for (int q = 0; q < 4; ++q) {
            float v = ps[rt][q];
            v += __shfl_xor(v, 1, 64);
            v += __shfl_xor(v, 2, 64);
            v += __shfl_xor(v, 4, 64);
            v += __shfl_xor(v, 8, 64);
            if (r == 0)
                atomicAdd(&denom[rowbase + rt * 16 + g * 4 + q], v);
        }

    // ---- last-block finalize (replaces separate finalize kernel) ----
    __syncthreads();   // vmcnt(0) drain: this block's denom atomics are issued
    __shared__ int islast;
    if (threadIdx.x == 0) {
        __threadfence();
        islast = (atomicAdd(ticket, 1u) == NBLOCKS_GEMM - 1) ? 1 : 0;
    }
    __syncthreads();
    if (islast) {
        int tid = threadIdx.x;
        float slog = 0.0f;
        #pragma unroll
        for (int u = 0; u < TN / 256; ++u) {
            float d = __hip_atomic_load(&denom[u * 256 + tid],
                                        __ATOMIC_RELAXED, __HIP_MEMORY_SCOPE_AGENT);
            slog += logf(d);
        }
        float spos = 0.0f;
        #pragma unroll
        for (int u = 0; u < 1024 / 256; ++u)
            spos += pos_part[u * 256 + tid];
        #pragma unroll
        for (int m = 1; m < 64; m <<= 1) {
            slog += __shfl_xor(slog, m, 64);
            spos += __shfl_xor(spos, m, 64);
        }
        __shared__ float redl[4], redp[4];
        if ((tid & 63) == 0) { redl[tid >> 6] = slog; redp[tid >> 6] = spos; }
        __syncthreads();
        if (tid == 0) {
            float tl = redl[0] + redl[1] + redl[2] + redl[3];
            float tp = redp[0] + redp[1] + redp[2] + redp[3];
            out[0] = (tl - 20.0f * tp) / (float)TN;
        }
    }
}

extern "C" void kernel_launch(void* const* d_in, const int* in_sizes, int n_in,
                              void* d_out, int out_size, void* d_ws, size_t ws_size,
                              hipStream_t stream) {
    const float* anchor = (const float*)d_in[0];
    const float* target = (const float*)d_in[1];
    float* denom       = (float*)d_ws;
    float* pos_part    = denom + TN;                  // 1024 entries
    unsigned* ticket   = (unsigned*)(pos_part + 1024); // float idx 9216
    ushort* z          = (ushort*)((char*)d_ws + Z_BYTE_OFF);

    prep_kernel<<<N_ROWS / 4, 256, 0, stream>>>(anchor, target, z, pos_part,
                                                denom, ticket);
    simgemm_kernel<<<dim3(TN / 64, TN / 1024), 256, 0, stream>>>(
        z, denom, pos_part, ticket, (float*)d_out);
}

// Round 7
// 144.663 us; speedup vs baseline: 1.3604x; 1.3604x over previous
//
#include <hip/hip_runtime.h>

#define N_ROWS 4096
#define TN 8192      // 2N
#define DIM 128
// z is pre-scaled by sqrt(10*log2(e)) so MFMA yields 10*log2e*sim directly:
// exp(10*s) = exp2( (sqrt(c)*zi) . (sqrt(c)*zj) ),  c = 10*log2(e)
#define SQRT_C 3.79828266f

// ws layout: [0,8192) f32 denom | [8192,9216) f32 pos_part | [9216] u32 ticket
//            | z bf16 at byte 40960 (disjoint from ticket — R5 aliased them)
#define Z_BYTE_OFF 40960
#define NBLOCKS_GEMM 1024   // grid (64, 16)

typedef __attribute__((ext_vector_type(8))) short short8;
typedef __attribute__((ext_vector_type(4))) float f32x4;

static __device__ __forceinline__ ushort f2bf(float f) {
    union { float f; unsigned u; } a; a.f = f;
    unsigned r = a.u + 0x7FFF + ((a.u >> 16) & 1);  // round-to-nearest-even
    return (ushort)(r >> 16);
}

// --- Kernel A: normalize -> scaled bf16 z; positives partial; zero denom/ticket ---
__global__ __launch_bounds__(256) void prep_kernel(
    const float* __restrict__ anchor, const float* __restrict__ target,
    ushort* __restrict__ z, float* __restrict__ pos_part,
    float* __restrict__ denom, unsigned* __restrict__ ticket)
{
    if (threadIdx.x < 8) denom[blockIdx.x * 8 + threadIdx.x] = 0.0f;
    if (blockIdx.x == 0 && threadIdx.x == 8) *ticket = 0u;

    int wave = threadIdx.x >> 6;
    int lane = threadIdx.x & 63;
    int i    = blockIdx.x * 4 + wave;
    float2 a = ((const float2*)(anchor + (size_t)i * DIM))[lane];
    float2 t = ((const float2*)(target + (size_t)i * DIM))[lane];
    float sa = a.x * a.x + a.y * a.y;
    float st = t.x * t.x + t.y * t.y;
    float dt = a.x * t.x + a.y * t.y;
    #pragma unroll
    for (int m = 1; m < 64; m <<= 1) {
        sa += __shfl_xor(sa, m, 64);
        st += __shfl_xor(st, m, 64);
        dt += __shfl_xor(dt, m, 64);
    }
    float rsa = rsqrtf(fmaxf(sa, 1e-12f));
    float rst = rsqrtf(fmaxf(st, 1e-12f));
    float ka = rsa * SQRT_C, kt = rst * SQRT_C;
    ushort2 za, zt;
    za.x = f2bf(a.x * ka); za.y = f2bf(a.y * ka);
    zt.x = f2bf(t.x * kt); zt.y = f2bf(t.y * kt);
    ((ushort2*)(z + (size_t)i * DIM))[lane] = za;
    ((ushort2*)(z + (size_t)(i + N_ROWS) * DIM))[lane] = zt;
    __shared__ float red[4];
    if (lane == 0) red[wave] = dt * rsa * rst;
    __syncthreads();
    if (threadIdx.x == 0)
        pos_part[blockIdx.x] = red[0] + red[1] + red[2] + red[3];
}

// --- Kernel B: denom_i += sum_j!=i exp2(z_i.z_j); last block computes the loss ---
// Block: 128 rows x 512 cols. 4 waves stacked VERTICALLY: wave w owns rows
// [blk*128 + w*32, +32) x all 512 cols -> all waves stream the SAME B tiles
// (L1-shared, 4x less L2 traffic). A (32x128) pinned in VGPRs via asm
// keep-alive (defeats remat, R4/R6 evidence). B: 2-deep register ping-pong.
// NO launch_bounds min-waves: budget ~100 VGPR must not be capped (R3/R6 spills).
__global__ __launch_bounds__(256) void simgemm_kernel(
    const ushort* __restrict__ z, float* __restrict__ denom,
    const float* __restrict__ pos_part, unsigned* __restrict__ ticket,
    float* __restrict__ out)
{
    int wave = threadIdx.x >> 6;
    int lane = threadIdx.x & 63;
    int r = lane & 15;       // A/B row-within-tile; C col
    int g = lane >> 4;       // k-group; C row group
    int rowbase = blockIdx.x * 128 + wave * 32;
    int wcol    = blockIdx.y * 512;

    // A fragments: 32 rows x 128 k resident (32 VGPR), pinned
    short8 a[2][4];
    #pragma unroll
    for (int rt = 0; rt < 2; ++rt)
        #pragma unroll
        for (int kt = 0; kt < 4; ++kt) {
            a[rt][kt] = *(const short8*)(z + (size_t)(rowbase + rt * 16 + r) * DIM
                                           + kt * 32 + g * 8);
            asm volatile("" : "+v"(*(f32x4*)&a[rt][kt]));  // forbid remat
        }

    float ps[2][4];
    #pragma unroll
    for (int rt = 0; rt < 2; ++rt)
        #pragma unroll
        for (int q = 0; q < 4; ++q) ps[rt][q] = 0.0f;

    bool wavediag = ((unsigned)(rowbase - wcol) < 512u);
    const ushort* pb = z + (size_t)(wcol + r) * DIM + g * 8;

#define LOADB(buf, t)                                                  \
    {   const ushort* p_ = pb + (size_t)(t) * (16 * DIM);              \
        buf[0] = *(const short8*)(p_);                                 \
        buf[1] = *(const short8*)(p_ + 32);                            \
        buf[2] = *(const short8*)(p_ + 64);                            \
        buf[3] = *(const short8*)(p_ + 96); }

#define COMPUTE(t, b)                                                         \
    {   int c0 = wcol + (t) * 16;                                             \
        bool dtile = wavediag && ((unsigned)(c0 - rowbase) < 32u);            \
        if (!dtile) {                                                         \
            _Pragma("unroll")                                                 \
            for (int rt = 0; rt < 2; ++rt) {                                  \
                f32x4 acc = {0.f, 0.f, 0.f, 0.f};                             \
                _Pragma("unroll")                                             \
                for (int kt = 0; kt < 4; ++kt)                                \
                    acc = __builtin_amdgcn_mfma_f32_16x16x32_bf16(            \
                        a[rt][kt], b[kt], acc, 0, 0, 0);                      \
                _Pragma("unroll")                                             \
                for (int q = 0; q < 4; ++q)                                   \
                    ps[rt][q] += __builtin_amdgcn_exp2f(acc[q]);              \
            }                                                                 \
        } else {                                                              \
            int gcol = c0 + r;                                                \
            _Pragma("unroll")                                                 \
            for (int rt = 0; rt < 2; ++rt) {                                  \
                f32x4 acc = {0.f, 0.f, 0.f, 0.f};                             \
                _Pragma("unroll")                                             \
                for (int kt = 0; kt < 4; ++kt)                                \
                    acc = __builtin_amdgcn_mfma_f32_16x16x32_bf16(            \
                        a[rt][kt], b[kt], acc, 0, 0, 0);                      \
                _Pragma("unroll")                                             \
                for (int q = 0; q < 4; ++q) {                                 \
                    float e = __builtin_amdgcn_exp2f(acc[q]);                 \
                    int grow = rowbase + rt * 16 + g * 4 + q;                 \
                    ps[rt][q] += (grow == gcol) ? 0.0f : e;                   \
                }                                                             \
            }                                                                 \
        } }

    // 32 tiles per wave; 2-deep ping-pong (proven codegen shape, R2/R4)
    short8 b0[4], b1[4];
    LOADB(b0, 0);
    #pragma unroll
    for (int t = 0; t < 32; t += 2) {
        LOADB(b1, t + 1);
        COMPUTE(t, b0);
        if (t + 2 < 32) LOADB(b0, t + 2);
        COMPUTE(t + 1, b1);
    }
#undef LOADB
#undef COMPUTE

    // reduce across the 16 lanes sharing g, then one atomic per row
    #pragma unroll
    for (int rt = 0; rt < 2; ++rt)
        #pragma unroll
        for (int q = 0; q < 4; ++q) {
            float v = ps[rt][q];
            v += __shfl_xor(v, 1, 64);
            v += __shfl_xor(v, 2, 64);
            v += __shfl_xor(v, 4, 64);
            v += __shfl_xor(v, 8, 64);
            if (r == 0)
                atomicAdd(&denom[rowbase + rt * 16 + g * 4 + q], v);
        }

    // ---- last-block finalize ----
    __syncthreads();
    __shared__ int islast;
    if (threadIdx.x == 0) {
        __threadfence();
        islast = (atomicAdd(ticket, 1u) == NBLOCKS_GEMM - 1) ? 1 : 0;
    }
    __syncthreads();
    if (islast) {
        int tid = threadIdx.x;
        float slog = 0.0f;
        #pragma unroll
        for (int u = 0; u < TN / 256; ++u) {
            float d = __hip_atomic_load(&denom[u * 256 + tid],
                                        __ATOMIC_RELAXED, __HIP_MEMORY_SCOPE_AGENT);
            slog += logf(d);
        }
        float spos = 0.0f;
        #pragma unroll
        for (int u = 0; u < 1024 / 256; ++u)
            spos += pos_part[u * 256 + tid];
        #pragma unroll
        for (int m = 1; m < 64; m <<= 1) {
            slog += __shfl_xor(slog, m, 64);
            spos += __shfl_xor(spos, m, 64);
        }
        __shared__ float redl[4], redp[4];
        if ((tid & 63) == 0) { redl[tid >> 6] = slog; redp[tid >> 6] = spos; }
        __syncthreads();
        if (tid == 0) {
            float tl = redl[0] + redl[1] + redl[2] + redl[3];
            float tp = redp[0] + redp[1] + redp[2] + redp[3];
            out[0] = (tl - 20.0f * tp) / (float)TN;
        }
    }
}

extern "C" void kernel_launch(void* const* d_in, const int* in_sizes, int n_in,
                              void* d_out, int out_size, void* d_ws, size_t ws_size,
                              hipStream_t stream) {
    const float* anchor = (const float*)d_in[0];
    const float* target = (const float*)d_in[1];
    float* denom       = (float*)d_ws;
    float* pos_part    = denom + TN;                   // 1024 entries
    unsigned* ticket   = (unsigned*)(pos_part + 1024); // float idx 9216
    ushort* z          = (ushort*)((char*)d_ws + Z_BYTE_OFF);

    prep_kernel<<<N_ROWS / 4, 256, 0, stream>>>(anchor, target, z, pos_part,
                                                denom, ticket);
    simgemm_kernel<<<dim3(TN / 128, TN / 512), 256, 0, stream>>>(
        z, denom, pos_part, ticket, (float*)d_out);
}